// Round 6
// baseline (2782.324 us; speedup 1.0000x reference)
//
#include <hip/hip_runtime.h>
#include <math.h>

#define Nn 2048
#define Dd 128
#define Ee 8
#define NIT 8
#define KT (Nn*Ee)   // 16384
#define KSPLIT 16
#define NBLK 256

typedef __bf16 bf16;
typedef __attribute__((ext_vector_type(8))) __bf16 bf16x8;
typedef __attribute__((ext_vector_type(4))) float f32x4;

__device__ __forceinline__ f32x4 mfma16(bf16x8 a, bf16x8 b, f32x4 c){
    return __builtin_amdgcn_mfma_f32_16x16x32_bf16(a, b, c, 0, 0, 0);
}

// Sense-reversing grid barrier, device scope. Requires all NBLK blocks
// co-resident (NBLK=256 = #CUs, 1 block/CU). __threadfence() provides the
// agent-scope release/acquire (L2 writeback / L1+L2 invalidate on gfx950).
__device__ __forceinline__ void gbar(unsigned* bar){
    __syncthreads();
    if (threadIdx.x == 0){
        __threadfence();
        unsigned g = __hip_atomic_load(&bar[1], __ATOMIC_RELAXED, __HIP_MEMORY_SCOPE_AGENT);
        unsigned a = __hip_atomic_fetch_add(&bar[0], 1u, __ATOMIC_ACQ_REL, __HIP_MEMORY_SCOPE_AGENT);
        if (a == NBLK-1u){
            __hip_atomic_store(&bar[0], 0u, __ATOMIC_RELAXED, __HIP_MEMORY_SCOPE_AGENT);
            __hip_atomic_store(&bar[1], g+1u, __ATOMIC_RELEASE, __HIP_MEMORY_SCOPE_AGENT);
        } else {
            while (__hip_atomic_load(&bar[1], __ATOMIC_ACQUIRE, __HIP_MEMORY_SCOPE_AGENT) == g)
                __builtin_amdgcn_s_sleep(2);
        }
        __threadfence();
    }
    __syncthreads();
}

// ---------------------------------------------------------------------------
// Prep (fp32 inputs): h fp32 master + bf16 copy; bf16-transposed weights.
// ---------------------------------------------------------------------------
__global__ __launch_bounds__(256) void k_prep(
    const float* __restrict__ node, const float* __restrict__ Wmsg,
    const float* __restrict__ Wi,   const float* __restrict__ Wh,
    const float* __restrict__ Ar,
    float* __restrict__ h32, bf16* __restrict__ hb,
    bf16* __restrict__ WmT, bf16* __restrict__ WiT, bf16* __restrict__ WhT,
    bf16* __restrict__ ArT)
{
    int tid = blockIdx.x*256 + threadIdx.x;
    int stride = gridDim.x*256;
    for (int i = tid; i < Nn*Dd; i += stride){
        float v = node[i]; h32[i] = v; hb[i] = (bf16)v;
    }
    for (int i = tid; i < Ee*Dd*Dd; i += stride){
        int e = i >> 14; int r = i & 16383; int h = r >> 7; int d = r & 127;
        WmT[i] = (bf16)Wmsg[e*Dd*Dd + d*Dd + h];
    }
    for (int i = tid; i < 384*Dd; i += stride){
        int j = i >> 7; int d = i & 127;
        WiT[i] = (bf16)Wi[d*384 + j];
        WhT[i] = (bf16)Wh[d*384 + j];
    }
    for (int i = tid; i < Dd*Dd; i += stride){
        int h = i >> 7; int d = i & 127;
        ArT[i] = (bf16)Ar[d*Dd + h];
    }
}

// ======================== mega-kernel phases ===============================

static __device__ __forceinline__ void phase_conv(
    int bid, const float* __restrict__ edge, bf16* __restrict__ edge_bf)
{
    const size_t total = (size_t)Nn*Nn*Ee;
    size_t base = ((size_t)bid*256 + threadIdx.x)*8;
    size_t stride = (size_t)NBLK*256*8;
    for (size_t i = base; i < total; i += stride){
        f32x4 v0 = *(const f32x4*)&edge[i];
        f32x4 v1 = *(const f32x4*)&edge[i+4];
        bf16x8 o;
        for (int j = 0; j < 4; j++){ o[j] = (bf16)v0[j]; o[j+4] = (bf16)v1[j]; }
        *(bf16x8*)&edge_bf[i] = o;
    }
}

// Pt[h][s*8+e] = (hb @ W_e)[s][h]; bid -> (s-tile of 64, h-tile of 16)
static __device__ __forceinline__ void phase_perE(
    int bid, const bf16* __restrict__ hb, const bf16* __restrict__ WmT,
    bf16* __restrict__ Pt, char* smem)
{
    bf16 (*Blds)[16][136] = (bf16(*)[16][136])smem;   // 34816 B
    const int s0 = (bid & 31) * 64;
    const int h0 = (bid >> 5) * 16;
    const int tid = threadIdx.x;
    for (int i = 0; i < 8; i++){
        int idx = tid + i*256;
        int e = idx >> 8, row = (idx >> 4) & 15, c = idx & 15;
        *(bf16x8*)&Blds[e][row][c*8] =
            *(const bf16x8*)&WmT[e*Dd*Dd + (h0+row)*Dd + c*8];
    }
    __syncthreads();
    const int lane = tid & 63, wave = tid >> 6;
    const int quad = lane >> 4, l16 = lane & 15;
    const int srow = s0 + wave*16 + l16;
    f32x4 acc[Ee];
    for (int e = 0; e < Ee; e++) acc[e] = (f32x4){0.f,0.f,0.f,0.f};
    for (int kk = 0; kk < 4; kk++){
        int k0 = kk*32 + quad*8;
        bf16x8 a = *(const bf16x8*)&hb[srow*Dd + k0];
        for (int e = 0; e < Ee; e++){
            bf16x8 b = *(const bf16x8*)&Blds[e][l16][k0];
            acc[e] = mfma16(a, b, acc[e]);
        }
    }
    const int h = h0 + l16;
    for (int r = 0; r < 4; r++){
        int s = s0 + wave*16 + quad*4 + r;
        bf16x8 po;
        for (int e = 0; e < Ee; e++) po[e] = (bf16)acc[e][r];
        *(bf16x8*)&Pt[(size_t)h*KT + s*Ee] = po;
    }
}

// msgP[ks][t][h] partial GEMM; bid -> (t-tile of 128, ksplit)
static __device__ __forceinline__ void phase_msgG(
    int bid, const bf16* __restrict__ edge_bf, const bf16* __restrict__ Pt,
    float* __restrict__ msgP, char* smem)
{
    bf16 (*Alds)[1032] = (bf16(*)[1032])smem;          // 16512 B
    bf16 (*Blds)[72]   = (bf16(*)[72])(smem + 16512);  // 18432 B
    const int t0 = (bid & 15) * 128;
    const int kbase = (bid >> 4) * (KT/KSPLIT);
    const int tid = threadIdx.x;
    const int lane = tid & 63, wave = tid >> 6;
    const int quad = lane >> 4, l16 = lane & 15;
    const int wm = wave & 1, wn = wave >> 1;

    f32x4 acc[4][4];
    for (int mt = 0; mt < 4; mt++)
        for (int nt = 0; nt < 4; nt++) acc[mt][nt] = (f32x4){0.f,0.f,0.f,0.f};

    for (int ch = 0; ch < 16; ch++){
        const int kc = kbase + ch*64;
        const int sb = kc >> 3;
        for (int i = 0; i < 4; i++){
            int idx = tid + i*256;
            int sl = idx >> 7, off = idx & 127;
            *(bf16x8*)&Alds[sl][off*8] =
                *(const bf16x8*)&edge_bf[(size_t)(sb+sl)*(Nn*Ee) + (size_t)(t0+off)*Ee];
        }
        for (int i = 0; i < 4; i++){
            int idx = tid + i*256;
            int row = idx >> 3, c = idx & 7;
            *(bf16x8*)&Blds[row][c*8] =
                *(const bf16x8*)&Pt[(size_t)row*KT + kc + c*8];
        }
        __syncthreads();
        for (int kk = 0; kk < 2; kk++){
            const int sl = kk*4 + quad;
            const int klb = kk*32 + quad*8;
            bf16x8 a[4], b[4];
            for (int mt = 0; mt < 4; mt++){
                int tp = wm*64 + mt*16 + l16;
                a[mt] = *(const bf16x8*)&Alds[sl][tp*8];
            }
            for (int nt = 0; nt < 4; nt++){
                int n = wn*64 + nt*16 + l16;
                b[nt] = *(const bf16x8*)&Blds[n][klb];
            }
            for (int mt = 0; mt < 4; mt++)
                for (int nt = 0; nt < 4; nt++)
                    acc[mt][nt] = mfma16(a[mt], b[nt], acc[mt][nt]);
        }
        __syncthreads();
    }
    float* dst = msgP + (size_t)(bid >> 4)*Nn*Dd;
    for (int mt = 0; mt < 4; mt++){
        for (int nt = 0; nt < 4; nt++){
            int h = wn*64 + nt*16 + l16;
            for (int r = 0; r < 4; r++){
                int t = t0 + wm*64 + mt*16 + quad*4 + r;
                dst[(size_t)t*Dd + h] = acc[mt][nt][r];
            }
        }
    }
}

// GRU for 16 t-rows (bid<128). msgP reduced once into LDS (padded).
static __device__ __forceinline__ void phase_gru(
    int bid, const float* __restrict__ msgP, const bf16* __restrict__ WiT,
    const bf16* __restrict__ WhT, const float* __restrict__ bmsg,
    const float* __restrict__ bgru, float* __restrict__ h32,
    bf16* __restrict__ hb, char* smem)
{
    bf16 (*stage)[40] = (bf16(*)[40])smem;              // 30720 B
    float (*Gs)[388]  = (float(*)[388])(smem + 30720);  // 24832 B (msum lives in cols 0..127 first)
    float (*Ghn)[132] = (float(*)[132])(smem + 55552);  //  8448 B -> 64000 total
    const int t0 = bid * 16;
    const int tid = threadIdx.x;
    // parallel reduction: msum[m][jd] = bmsg[jd] + sum_p msgP[p][t0+m][jd]
    for (int i = tid; i < 16*Dd; i += 256){
        int m = i >> 7, jd = i & 127;
        float s = bmsg[jd];
        const float* mp = &msgP[(size_t)(t0+m)*Dd + jd];
        for (int p = 0; p < KSPLIT; p++) s += mp[(size_t)p*Nn*Dd];
        Gs[m][jd] = s;
    }
    __syncthreads();
    const int lane = tid & 63, wave = tid >> 6;
    const int quad = lane >> 4, l16 = lane & 15;
    f32x4 accA[6], accB[6];
    for (int i = 0; i < 6; i++){ accA[i] = (f32x4){0.f,0.f,0.f,0.f}; accB[i] = (f32x4){0.f,0.f,0.f,0.f}; }
    for (int mat = 0; mat < 2; mat++){
        const bf16* WT = mat == 0 ? WiT : WhT;
        for (int kc = 0; kc < 4; kc++){
            for (int i = 0; i < 6; i++){
                int idx = tid + i*256; int row = idx >> 2, c = idx & 3;
                *(bf16x8*)&stage[row][c*8] = *(const bf16x8*)&WT[row*Dd + kc*32 + c*8];
            }
            __syncthreads();
            int k0 = kc*32 + quad*8;
            bf16x8 a;
            if (mat == 0){
                const float* gp = &Gs[l16][k0];
                for (int j = 0; j < 8; j++) a[j] = (bf16)gp[j];
            } else {
                a = *(const bf16x8*)&hb[(t0 + l16)*Dd + k0];
            }
            for (int tt = 0; tt < 6; tt++){
                int T = wave*6 + tt;
                bf16x8 b = *(const bf16x8*)&stage[T*16 + l16][quad*8];
                if (mat == 0 || T < 16) accA[tt] = mfma16(a, b, accA[tt]);
                else                    accB[tt] = mfma16(a, b, accB[tt]);
            }
            __syncthreads();
        }
    }
    for (int tt = 0; tt < 6; tt++){
        int T = wave*6 + tt;
        int j = T*16 + l16;
        for (int r = 0; r < 4; r++){
            int m = quad*4 + r;
            Gs[m][j] = accA[tt][r];
            if (T >= 16) Ghn[m][j - 256] = accB[tt][r];
        }
    }
    __syncthreads();
    for (int i = 0; i < 8; i++){
        int cell = tid + i*256;
        int m = cell >> 7, jd = cell & 127;
        int t = t0 + m;
        float xr = Gs[m][jd]       + bgru[jd];
        float xz = Gs[m][jd + 128] + bgru[jd + 128];
        float xn = Gs[m][jd + 256] + bgru[jd + 256];
        float r = 1.f / (1.f + expf(-xr));
        float z = 1.f / (1.f + expf(-xz));
        float n = tanhf(xn + r * Ghn[m][jd]);
        float ho = h32[t*Dd + jd];
        float hnew = (1.f - z) * n + z * ho;
        h32[t*Dd + jd] = hnew;
        hb [t*Dd + jd] = (bf16)hnew;
    }
}

// t1 = hb @ A_readout (bid<32, s-tile of 64)
static __device__ __forceinline__ void phase_read1(
    int bid, const bf16* __restrict__ hb, const bf16* __restrict__ ArT,
    bf16* __restrict__ t1, char* smem)
{
    bf16 (*Blds)[136] = (bf16(*)[136])smem;             // 34816 B
    const int s0 = bid * 64;
    const int tid = threadIdx.x;
    for (int i = 0; i < 8; i++){
        int idx = tid + i*256; int row = idx >> 4, c = idx & 15;
        *(bf16x8*)&Blds[row][c*8] = *(const bf16x8*)&ArT[row*Dd + c*8];
    }
    __syncthreads();
    const int lane = tid & 63, wave = tid >> 6;
    const int quad = lane >> 4, l16 = lane & 15;
    const int srow = s0 + wave*16 + l16;
    f32x4 acc[8];
    for (int nt = 0; nt < 8; nt++) acc[nt] = (f32x4){0.f,0.f,0.f,0.f};
    for (int kk = 0; kk < 4; kk++){
        int k0 = kk*32 + quad*8;
        bf16x8 a = *(const bf16x8*)&hb[srow*Dd + k0];
        for (int nt = 0; nt < 8; nt++){
            bf16x8 b = *(const bf16x8*)&Blds[nt*16 + l16][k0];
            acc[nt] = mfma16(a, b, acc[nt]);
        }
    }
    for (int nt = 0; nt < 8; nt++){
        int h = nt*16 + l16;
        for (int r = 0; r < 4; r++){
            int s = s0 + wave*16 + quad*4 + r;
            t1[s*Dd + h] = (bf16)acc[nt][r];
        }
    }
}

// logits[i][j] = sum_d t1[i][d]*hb[j][d]; bid -> (i-tile 128, j-tile 128)
static __device__ __forceinline__ void phase_read2(
    int bid, const bf16* __restrict__ t1, const bf16* __restrict__ hb,
    float* __restrict__ out)
{
    const int i0 = (bid & 15) * 128, j0 = (bid >> 4) * 128;
    const int tid = threadIdx.x;
    const int lane = tid & 63, wave = tid >> 6;
    const int quad = lane >> 4, l16 = lane & 15;
    const int wm = wave & 1, wn = wave >> 1;
    f32x4 acc[4][4];
    for (int mt = 0; mt < 4; mt++)
        for (int nt = 0; nt < 4; nt++) acc[mt][nt] = (f32x4){0.f,0.f,0.f,0.f};
    for (int kk = 0; kk < 4; kk++){
        int k0 = kk*32 + quad*8;
        bf16x8 a[4], b[4];
        for (int mt = 0; mt < 4; mt++)
            a[mt] = *(const bf16x8*)&t1[(size_t)(i0 + wm*64 + mt*16 + l16)*Dd + k0];
        for (int nt = 0; nt < 4; nt++)
            b[nt] = *(const bf16x8*)&hb[(size_t)(j0 + wn*64 + nt*16 + l16)*Dd + k0];
        for (int mt = 0; mt < 4; mt++)
            for (int nt = 0; nt < 4; nt++)
                acc[mt][nt] = mfma16(a[mt], b[nt], acc[mt][nt]);
    }
    for (int mt = 0; mt < 4; mt++){
        for (int nt = 0; nt < 4; nt++){
            int j = j0 + wn*64 + nt*16 + l16;
            for (int r = 0; r < 4; r++){
                int i = i0 + wm*64 + mt*16 + quad*4 + r;
                out[(size_t)i*Nn + j] = acc[mt][nt][r];
            }
        }
    }
}

// ---------------------------------------------------------------------------
// Persistent mega-kernel: conv + NIT x (perE, msgG, gru) + read1 + read2,
// grid barriers between phases. 256 blocks, 1/CU.
// ---------------------------------------------------------------------------
__global__ __launch_bounds__(256, 1) void k_mega(
    const float* __restrict__ edge, bf16* __restrict__ edge_bf,
    const bf16* __restrict__ WmT, bf16* __restrict__ Pt,
    float* __restrict__ msgP,
    const bf16* __restrict__ WiT, const bf16* __restrict__ WhT,
    const float* __restrict__ bmsg, const float* __restrict__ bgru,
    float* __restrict__ h32, bf16* __restrict__ hb,
    const bf16* __restrict__ ArT, bf16* __restrict__ t1,
    float* __restrict__ out, unsigned* __restrict__ bar)
{
    __shared__ __align__(16) char smem[64000];
    const int bid = blockIdx.x;

    phase_conv(bid, edge, edge_bf);
    phase_perE(bid, hb, WmT, Pt, smem);
    gbar(bar);
    for (int it = 0; it < NIT; it++){
        phase_msgG(bid, edge_bf, Pt, msgP, smem);
        gbar(bar);
        if (bid < 128) phase_gru(bid, msgP, WiT, WhT, bmsg, bgru, h32, hb, smem);
        gbar(bar);
        if (it < NIT-1){
            phase_perE(bid, hb, WmT, Pt, smem);
            gbar(bar);
        }
    }
    if (bid < 32) phase_read1(bid, hb, ArT, t1, smem);
    gbar(bar);
    phase_read2(bid, t1, hb, out);
}

// ---------------------------------------------------------------------------
extern "C" void kernel_launch(void* const* d_in, const int* in_sizes, int n_in,
                              void* d_out, int out_size, void* d_ws, size_t ws_size,
                              hipStream_t stream)
{
    const float* node = (const float*)d_in[0];
    const float* edge = (const float*)d_in[1];
    const float* Wmsg = (const float*)d_in[2];
    const float* bmsg = (const float*)d_in[3];
    const float* Wi   = (const float*)d_in[4];
    const float* Wh   = (const float*)d_in[5];
    const float* bgru = (const float*)d_in[6];
    const float* Ar   = (const float*)d_in[7];
    float* out = (float*)d_out;

    char* ws = (char*)d_ws;
    bf16*  edge_bf = (bf16*)ws;          ws += (size_t)Nn*Nn*Ee*2;      // 64 MiB
    float* msgP = (float*)ws;            ws += (size_t)KSPLIT*Nn*Dd*4;  // 16 MiB
    bf16*  Pt  = (bf16*)ws;              ws += (size_t)Dd*KT*2;         //  4 MiB
    float* h32 = (float*)ws;             ws += (size_t)Nn*Dd*4;
    bf16*  hb  = (bf16*)ws;              ws += (size_t)Nn*Dd*2;
    bf16*  WmT = (bf16*)ws;              ws += (size_t)Ee*Dd*Dd*2;
    bf16*  WiT = (bf16*)ws;              ws += (size_t)384*Dd*2;
    bf16*  WhT = (bf16*)ws;              ws += (size_t)384*Dd*2;
    bf16*  ArT = (bf16*)ws;              ws += (size_t)Dd*Dd*2;
    bf16*  t1  = (bf16*)ws;              ws += (size_t)Nn*Dd*2;
    unsigned* bar = (unsigned*)ws;       ws += 256;

    hipMemsetAsync(bar, 0, 2*sizeof(unsigned), stream);
    k_prep<<<dim3(256), 256, 0, stream>>>(node, Wmsg, Wi, Wh, Ar,
                                          h32, hb, WmT, WiT, WhT, ArT);
    k_mega<<<dim3(NBLK), 256, 0, stream>>>(edge, edge_bf, WmT, Pt, msgP,
                                           WiT, WhT, bmsg, bgru, h32, hb,
                                           ArT, t1, out, bar);
}

// Round 7
// 2636.818 us; speedup vs baseline: 1.0552x; 1.0552x over previous
//
#include <hip/hip_runtime.h>
#include <math.h>

#define Nn 2048
#define Dd 128
#define Ee 8
#define NIT 8
#define KT (Nn*Ee)   // 16384
#define KSPLIT 32
#define NBLK 512

typedef __bf16 bf16;
typedef __attribute__((ext_vector_type(8))) __bf16 bf16x8;
typedef __attribute__((ext_vector_type(4))) float f32x4;

__device__ __forceinline__ f32x4 mfma16(bf16x8 a, bf16x8 b, f32x4 c){
    return __builtin_amdgcn_mfma_f32_16x16x32_bf16(a, b, c, 0, 0, 0);
}

// Sense-reversing grid barrier. Poll with RELAXED (no per-poll cache
// invalidate — the R6 85us/barrier bug); one acquire threadfence on exit.
// bar[1] store is RELEASE so the bar[0] reset is ordered before the bump.
__device__ __forceinline__ void gbar(unsigned* bar){
    __syncthreads();
    if (threadIdx.x == 0){
        __threadfence();   // release this block's writes
        unsigned g = __hip_atomic_load(&bar[1], __ATOMIC_RELAXED, __HIP_MEMORY_SCOPE_AGENT);
        unsigned a = __hip_atomic_fetch_add(&bar[0], 1u, __ATOMIC_RELAXED, __HIP_MEMORY_SCOPE_AGENT);
        if (a == NBLK-1u){
            __hip_atomic_store(&bar[0], 0u, __ATOMIC_RELAXED, __HIP_MEMORY_SCOPE_AGENT);
            __hip_atomic_store(&bar[1], g+1u, __ATOMIC_RELEASE, __HIP_MEMORY_SCOPE_AGENT);
        } else {
            while (__hip_atomic_load(&bar[1], __ATOMIC_RELAXED, __HIP_MEMORY_SCOPE_AGENT) == g)
                __builtin_amdgcn_s_sleep(8);
        }
        __threadfence();   // acquire others' writes
    }
    __syncthreads();
}

// ---------------------------------------------------------------------------
// Prep (fp32 inputs): h fp32 master + bf16 copy; bf16-transposed weights.
// ---------------------------------------------------------------------------
__global__ __launch_bounds__(256) void k_prep(
    const float* __restrict__ node, const float* __restrict__ Wmsg,
    const float* __restrict__ Wi,   const float* __restrict__ Wh,
    const float* __restrict__ Ar,
    float* __restrict__ h32, bf16* __restrict__ hb,
    bf16* __restrict__ WmT, bf16* __restrict__ WiT, bf16* __restrict__ WhT,
    bf16* __restrict__ ArT)
{
    int tid = blockIdx.x*256 + threadIdx.x;
    int stride = gridDim.x*256;
    for (int i = tid; i < Nn*Dd; i += stride){
        float v = node[i]; h32[i] = v; hb[i] = (bf16)v;
    }
    for (int i = tid; i < Ee*Dd*Dd; i += stride){
        int e = i >> 14; int r = i & 16383; int h = r >> 7; int d = r & 127;
        WmT[i] = (bf16)Wmsg[e*Dd*Dd + d*Dd + h];
    }
    for (int i = tid; i < 384*Dd; i += stride){
        int j = i >> 7; int d = i & 127;
        WiT[i] = (bf16)Wi[d*384 + j];
        WhT[i] = (bf16)Wh[d*384 + j];
    }
    for (int i = tid; i < Dd*Dd; i += stride){
        int h = i >> 7; int d = i & 127;
        ArT[i] = (bf16)Ar[d*Dd + h];
    }
}

// ======================== mega-kernel phases ===============================

static __device__ __forceinline__ void phase_conv(
    int bid, const float* __restrict__ edge, bf16* __restrict__ edge_bf)
{
    const size_t total = (size_t)Nn*Nn*Ee;
    size_t base = ((size_t)bid*256 + threadIdx.x)*8;
    size_t stride = (size_t)NBLK*256*8;
    for (size_t i = base; i < total; i += stride){
        f32x4 v0 = *(const f32x4*)&edge[i];
        f32x4 v1 = *(const f32x4*)&edge[i+4];
        bf16x8 o;
        for (int j = 0; j < 4; j++){ o[j] = (bf16)v0[j]; o[j+4] = (bf16)v1[j]; }
        *(bf16x8*)&edge_bf[i] = o;
    }
}

// Pt[h][s*8+e] = (hb @ W_e)[s][h]; active bid<256 -> (s-tile 64, h-tile 16)
static __device__ __forceinline__ void phase_perE(
    int bid, const bf16* __restrict__ hb, const bf16* __restrict__ WmT,
    bf16* __restrict__ Pt, char* smem)
{
    bf16 (*Blds)[16][136] = (bf16(*)[16][136])smem;   // 34816 B
    const int s0 = (bid & 31) * 64;
    const int h0 = (bid >> 5) * 16;
    const int tid = threadIdx.x;
    for (int i = 0; i < 8; i++){
        int idx = tid + i*256;
        int e = idx >> 8, row = (idx >> 4) & 15, c = idx & 15;
        *(bf16x8*)&Blds[e][row][c*8] =
            *(const bf16x8*)&WmT[e*Dd*Dd + (h0+row)*Dd + c*8];
    }
    __syncthreads();
    const int lane = tid & 63, wave = tid >> 6;
    const int quad = lane >> 4, l16 = lane & 15;
    const int srow = s0 + wave*16 + l16;
    f32x4 acc[Ee];
    for (int e = 0; e < Ee; e++) acc[e] = (f32x4){0.f,0.f,0.f,0.f};
    for (int kk = 0; kk < 4; kk++){
        int k0 = kk*32 + quad*8;
        bf16x8 a = *(const bf16x8*)&hb[srow*Dd + k0];
        for (int e = 0; e < Ee; e++){
            bf16x8 b = *(const bf16x8*)&Blds[e][l16][k0];
            acc[e] = mfma16(a, b, acc[e]);
        }
    }
    const int h = h0 + l16;
    for (int r = 0; r < 4; r++){
        int s = s0 + wave*16 + quad*4 + r;
        bf16x8 po;
        for (int e = 0; e < Ee; e++) po[e] = (bf16)acc[e][r];
        *(bf16x8*)&Pt[(size_t)h*KT + s*Ee] = po;
    }
}

// msgP[ks][t][h] partial GEMM; bid -> (t-tile of 128, ks of 32)
static __device__ __forceinline__ void phase_msgG(
    int bid, const bf16* __restrict__ edge_bf, const bf16* __restrict__ Pt,
    float* __restrict__ msgP, char* smem)
{
    bf16 (*Alds)[1032] = (bf16(*)[1032])smem;          // 16512 B
    bf16 (*Blds)[72]   = (bf16(*)[72])(smem + 16512);  // 18432 B
    const int t0 = (bid & 15) * 128;
    const int ks = bid >> 4;                            // 0..31
    const int kbase = ks * (KT/KSPLIT);                 // 512 k = 64 s
    const int tid = threadIdx.x;
    const int lane = tid & 63, wave = tid >> 6;
    const int quad = lane >> 4, l16 = lane & 15;
    const int wm = wave & 1, wn = wave >> 1;

    f32x4 acc[4][4];
    for (int mt = 0; mt < 4; mt++)
        for (int nt = 0; nt < 4; nt++) acc[mt][nt] = (f32x4){0.f,0.f,0.f,0.f};

    for (int ch = 0; ch < 8; ch++){
        const int kc = kbase + ch*64;
        const int sb = kc >> 3;
        for (int i = 0; i < 4; i++){
            int idx = tid + i*256;
            int sl = idx >> 7, off = idx & 127;
            *(bf16x8*)&Alds[sl][off*8] =
                *(const bf16x8*)&edge_bf[(size_t)(sb+sl)*(Nn*Ee) + (size_t)(t0+off)*Ee];
        }
        for (int i = 0; i < 4; i++){
            int idx = tid + i*256;
            int row = idx >> 3, c = idx & 7;
            *(bf16x8*)&Blds[row][c*8] =
                *(const bf16x8*)&Pt[(size_t)row*KT + kc + c*8];
        }
        __syncthreads();
        for (int kk = 0; kk < 2; kk++){
            const int sl = kk*4 + quad;
            const int klb = kk*32 + quad*8;
            bf16x8 a[4], b[4];
            for (int mt = 0; mt < 4; mt++){
                int tp = wm*64 + mt*16 + l16;
                a[mt] = *(const bf16x8*)&Alds[sl][tp*8];
            }
            for (int nt = 0; nt < 4; nt++){
                int n = wn*64 + nt*16 + l16;
                b[nt] = *(const bf16x8*)&Blds[n][klb];
            }
            for (int mt = 0; mt < 4; mt++)
                for (int nt = 0; nt < 4; nt++)
                    acc[mt][nt] = mfma16(a[mt], b[nt], acc[mt][nt]);
        }
        __syncthreads();
    }
    float* dst = msgP + (size_t)ks*Nn*Dd;
    for (int mt = 0; mt < 4; mt++){
        for (int nt = 0; nt < 4; nt++){
            int h = wn*64 + nt*16 + l16;
            for (int r = 0; r < 4; r++){
                int t = t0 + wm*64 + mt*16 + quad*4 + r;
                dst[(size_t)t*Dd + h] = acc[mt][nt][r];
            }
        }
    }
}

// GRU for 16 t-rows (active bid<128). msgP reduced once into LDS.
static __device__ __forceinline__ void phase_gru(
    int bid, const float* __restrict__ msgP, const bf16* __restrict__ WiT,
    const bf16* __restrict__ WhT, const float* __restrict__ bmsg,
    const float* __restrict__ bgru, float* __restrict__ h32,
    bf16* __restrict__ hb, char* smem)
{
    bf16 (*stage)[40] = (bf16(*)[40])smem;              // 30720 B
    float (*Gs)[388]  = (float(*)[388])(smem + 30720);  // 24832 B
    float (*Ghn)[132] = (float(*)[132])(smem + 55552);  //  8448 B -> 64000
    const int t0 = bid * 16;
    const int tid = threadIdx.x;
    for (int i = tid; i < 16*Dd; i += 256){
        int m = i >> 7, jd = i & 127;
        float s = bmsg[jd];
        const float* mp = &msgP[(size_t)(t0+m)*Dd + jd];
        for (int p = 0; p < KSPLIT; p++) s += mp[(size_t)p*Nn*Dd];
        Gs[m][jd] = s;
    }
    __syncthreads();
    const int lane = tid & 63, wave = tid >> 6;
    const int quad = lane >> 4, l16 = lane & 15;
    f32x4 accA[6], accB[6];
    for (int i = 0; i < 6; i++){ accA[i] = (f32x4){0.f,0.f,0.f,0.f}; accB[i] = (f32x4){0.f,0.f,0.f,0.f}; }
    for (int mat = 0; mat < 2; mat++){
        const bf16* WT = mat == 0 ? WiT : WhT;
        for (int kc = 0; kc < 4; kc++){
            for (int i = 0; i < 6; i++){
                int idx = tid + i*256; int row = idx >> 2, c = idx & 3;
                *(bf16x8*)&stage[row][c*8] = *(const bf16x8*)&WT[row*Dd + kc*32 + c*8];
            }
            __syncthreads();
            int k0 = kc*32 + quad*8;
            bf16x8 a;
            if (mat == 0){
                const float* gp = &Gs[l16][k0];
                for (int j = 0; j < 8; j++) a[j] = (bf16)gp[j];
            } else {
                a = *(const bf16x8*)&hb[(t0 + l16)*Dd + k0];
            }
            for (int tt = 0; tt < 6; tt++){
                int T = wave*6 + tt;
                bf16x8 b = *(const bf16x8*)&stage[T*16 + l16][quad*8];
                if (mat == 0 || T < 16) accA[tt] = mfma16(a, b, accA[tt]);
                else                    accB[tt] = mfma16(a, b, accB[tt]);
            }
            __syncthreads();
        }
    }
    for (int tt = 0; tt < 6; tt++){
        int T = wave*6 + tt;
        int j = T*16 + l16;
        for (int r = 0; r < 4; r++){
            int m = quad*4 + r;
            Gs[m][j] = accA[tt][r];
            if (T >= 16) Ghn[m][j - 256] = accB[tt][r];
        }
    }
    __syncthreads();
    for (int i = 0; i < 8; i++){
        int cell = tid + i*256;
        int m = cell >> 7, jd = cell & 127;
        int t = t0 + m;
        float xr = Gs[m][jd]       + bgru[jd];
        float xz = Gs[m][jd + 128] + bgru[jd + 128];
        float xn = Gs[m][jd + 256] + bgru[jd + 256];
        float r = 1.f / (1.f + expf(-xr));
        float z = 1.f / (1.f + expf(-xz));
        float n = tanhf(xn + r * Ghn[m][jd]);
        float ho = h32[t*Dd + jd];
        float hnew = (1.f - z) * n + z * ho;
        h32[t*Dd + jd] = hnew;
        hb [t*Dd + jd] = (bf16)hnew;
    }
}

// t1 = hb @ A_readout (active bid<32, s-tile of 64)
static __device__ __forceinline__ void phase_read1(
    int bid, const bf16* __restrict__ hb, const bf16* __restrict__ ArT,
    bf16* __restrict__ t1, char* smem)
{
    bf16 (*Blds)[136] = (bf16(*)[136])smem;
    const int s0 = bid * 64;
    const int tid = threadIdx.x;
    for (int i = 0; i < 8; i++){
        int idx = tid + i*256; int row = idx >> 4, c = idx & 15;
        *(bf16x8*)&Blds[row][c*8] = *(const bf16x8*)&ArT[row*Dd + c*8];
    }
    __syncthreads();
    const int lane = tid & 63, wave = tid >> 6;
    const int quad = lane >> 4, l16 = lane & 15;
    const int srow = s0 + wave*16 + l16;
    f32x4 acc[8];
    for (int nt = 0; nt < 8; nt++) acc[nt] = (f32x4){0.f,0.f,0.f,0.f};
    for (int kk = 0; kk < 4; kk++){
        int k0 = kk*32 + quad*8;
        bf16x8 a = *(const bf16x8*)&hb[srow*Dd + k0];
        for (int nt = 0; nt < 8; nt++){
            bf16x8 b = *(const bf16x8*)&Blds[nt*16 + l16][k0];
            acc[nt] = mfma16(a, b, acc[nt]);
        }
    }
    for (int nt = 0; nt < 8; nt++){
        int h = nt*16 + l16;
        for (int r = 0; r < 4; r++){
            int s = s0 + wave*16 + quad*4 + r;
            t1[s*Dd + h] = (bf16)acc[nt][r];
        }
    }
}

// logits[i][j] = sum_d t1[i][d]*hb[j][d]; active bid<256 -> (i,j tiles of 128)
static __device__ __forceinline__ void phase_read2(
    int bid, const bf16* __restrict__ t1, const bf16* __restrict__ hb,
    float* __restrict__ out)
{
    const int i0 = (bid & 15) * 128, j0 = (bid >> 4) * 128;
    const int tid = threadIdx.x;
    const int lane = tid & 63, wave = tid >> 6;
    const int quad = lane >> 4, l16 = lane & 15;
    const int wm = wave & 1, wn = wave >> 1;
    f32x4 acc[4][4];
    for (int mt = 0; mt < 4; mt++)
        for (int nt = 0; nt < 4; nt++) acc[mt][nt] = (f32x4){0.f,0.f,0.f,0.f};
    for (int kk = 0; kk < 4; kk++){
        int k0 = kk*32 + quad*8;
        bf16x8 a[4], b[4];
        for (int mt = 0; mt < 4; mt++)
            a[mt] = *(const bf16x8*)&t1[(size_t)(i0 + wm*64 + mt*16 + l16)*Dd + k0];
        for (int nt = 0; nt < 4; nt++)
            b[nt] = *(const bf16x8*)&hb[(size_t)(j0 + wn*64 + nt*16 + l16)*Dd + k0];
        for (int mt = 0; mt < 4; mt++)
            for (int nt = 0; nt < 4; nt++)
                acc[mt][nt] = mfma16(a[mt], b[nt], acc[mt][nt]);
    }
    for (int mt = 0; mt < 4; mt++){
        for (int nt = 0; nt < 4; nt++){
            int j = j0 + wn*64 + nt*16 + l16;
            for (int r = 0; r < 4; r++){
                int i = i0 + wm*64 + mt*16 + quad*4 + r;
                out[(size_t)i*Nn + j] = acc[mt][nt][r];
            }
        }
    }
}

// ---------------------------------------------------------------------------
// Persistent mega-kernel: 512 blocks, 2/CU (8 waves/CU for latency hiding).
// ---------------------------------------------------------------------------
__global__ __launch_bounds__(256, 2) void k_mega(
    const float* __restrict__ edge, bf16* __restrict__ edge_bf,
    const bf16* __restrict__ WmT, bf16* __restrict__ Pt,
    float* __restrict__ msgP,
    const bf16* __restrict__ WiT, const bf16* __restrict__ WhT,
    const float* __restrict__ bmsg, const float* __restrict__ bgru,
    float* __restrict__ h32, bf16* __restrict__ hb,
    const bf16* __restrict__ ArT, bf16* __restrict__ t1,
    float* __restrict__ out, unsigned* __restrict__ bar)
{
    __shared__ __align__(16) char smem[64000];
    const int bid = blockIdx.x;

    phase_conv(bid, edge, edge_bf);
    if (bid < 256) phase_perE(bid, hb, WmT, Pt, smem);
    gbar(bar);
    for (int it = 0; it < NIT; it++){
        phase_msgG(bid, edge_bf, Pt, msgP, smem);
        gbar(bar);
        if (bid < 128) phase_gru(bid, msgP, WiT, WhT, bmsg, bgru, h32, hb, smem);
        gbar(bar);
        if (it < NIT-1){
            if (bid < 256) phase_perE(bid, hb, WmT, Pt, smem);
            gbar(bar);
        }
    }
    if (bid < 32) phase_read1(bid, hb, ArT, t1, smem);
    gbar(bar);
    if (bid < 256) phase_read2(bid, t1, hb, out);
}

// ---------------------------------------------------------------------------
extern "C" void kernel_launch(void* const* d_in, const int* in_sizes, int n_in,
                              void* d_out, int out_size, void* d_ws, size_t ws_size,
                              hipStream_t stream)
{
    const float* node = (const float*)d_in[0];
    const float* edge = (const float*)d_in[1];
    const float* Wmsg = (const float*)d_in[2];
    const float* bmsg = (const float*)d_in[3];
    const float* Wi   = (const float*)d_in[4];
    const float* Wh   = (const float*)d_in[5];
    const float* bgru = (const float*)d_in[6];
    const float* Ar   = (const float*)d_in[7];
    float* out = (float*)d_out;

    char* ws = (char*)d_ws;
    bf16*  edge_bf = (bf16*)ws;          ws += (size_t)Nn*Nn*Ee*2;      // 64 MiB
    float* msgP = (float*)ws;            ws += (size_t)KSPLIT*Nn*Dd*4;  // 32 MiB
    bf16*  Pt  = (bf16*)ws;              ws += (size_t)Dd*KT*2;         //  4 MiB
    float* h32 = (float*)ws;             ws += (size_t)Nn*Dd*4;
    bf16*  hb  = (bf16*)ws;              ws += (size_t)Nn*Dd*2;
    bf16*  WmT = (bf16*)ws;              ws += (size_t)Ee*Dd*Dd*2;
    bf16*  WiT = (bf16*)ws;              ws += (size_t)384*Dd*2;
    bf16*  WhT = (bf16*)ws;              ws += (size_t)384*Dd*2;
    bf16*  ArT = (bf16*)ws;              ws += (size_t)Dd*Dd*2;
    bf16*  t1  = (bf16*)ws;              ws += (size_t)Nn*Dd*2;
    unsigned* bar = (unsigned*)ws;       ws += 256;

    hipMemsetAsync(bar, 0, 2*sizeof(unsigned), stream);
    k_prep<<<dim3(256), 256, 0, stream>>>(node, Wmsg, Wi, Wh, Ar,
                                          h32, hb, WmT, WiT, WhT, ArT);
    k_mega<<<dim3(NBLK), 256, 0, stream>>>(edge, edge_bf, WmT, Pt, msgP,
                                           WiT, WhT, bmsg, bgru, h32, hb,
                                           ArT, t1, out, bar);
}

// Round 8
// 1464.368 us; speedup vs baseline: 1.9000x; 1.8007x over previous
//
#include <hip/hip_runtime.h>
#include <math.h>

#define Nn 2048
#define Dd 128
#define Ee 8
#define NIT 8
#define KT (Nn*Ee)   // 16384
#define KSPLIT 32
#define NBLK 512

typedef __bf16 bf16;
typedef unsigned int u32;
typedef unsigned short u16;
typedef __attribute__((ext_vector_type(8))) __bf16 bf16x8;
typedef __attribute__((ext_vector_type(4))) float f32x4;

__device__ __forceinline__ f32x4 mfma16(bf16x8 a, bf16x8 b, f32x4 c){
    return __builtin_amdgcn_mfma_f32_16x16x32_bf16(a, b, c, 0, 0, 0);
}

// ---- agent-scope relaxed (coherence-point) accessors: no fence needed ----
__device__ __forceinline__ u32  ldg_u32(const u32* p){ return __hip_atomic_load(p, __ATOMIC_RELAXED, __HIP_MEMORY_SCOPE_AGENT); }
__device__ __forceinline__ void stg_u32(u32* p, u32 v){ __hip_atomic_store(p, v, __ATOMIC_RELAXED, __HIP_MEMORY_SCOPE_AGENT); }
__device__ __forceinline__ float ldg_f32(const float* p){ return __hip_atomic_load(p, __ATOMIC_RELAXED, __HIP_MEMORY_SCOPE_AGENT); }
__device__ __forceinline__ void stg_f32(float* p, float v){ __hip_atomic_store(p, v, __ATOMIC_RELAXED, __HIP_MEMORY_SCOPE_AGENT); }
__device__ __forceinline__ void stg_u16(u16* p, u16 v){ __hip_atomic_store(p, v, __ATOMIC_RELAXED, __HIP_MEMORY_SCOPE_AGENT); }
__device__ __forceinline__ bf16x8 ldg_frag(const bf16* p){
    const u32* q = (const u32*)p;
    union { u32 u[4]; bf16x8 v; } w;
    w.u[0]=ldg_u32(q); w.u[1]=ldg_u32(q+1); w.u[2]=ldg_u32(q+2); w.u[3]=ldg_u32(q+3);
    return w.v;
}
__device__ __forceinline__ u16 bf_bits(bf16 b){ union{ bf16 b; u16 u;} w; w.b=b; return w.u; }

// Fence-FREE hierarchical barrier: monotone counters (no resets), relaxed
// atomics only. Data visibility comes from (a) all cross-block traffic using
// agent-scope atomics (coherence point), (b) __syncthreads' vmcnt(0) drain
// before arrival. `fence`=true only once, after conv, to flush cached
// edge_bf writes (the only cached cross-block buffer; written exactly once).
__device__ __forceinline__ void gbar(unsigned* bar, unsigned bk, bool fence){
    __syncthreads();
    if (threadIdx.x == 0){
        if (fence) __threadfence();
        const unsigned gid = blockIdx.x >> 5;                  // 16 groups of 32
        unsigned a = __hip_atomic_fetch_add(&bar[gid*32], 1u, __ATOMIC_RELAXED, __HIP_MEMORY_SCOPE_AGENT);
        if (a == bk*32u + 31u){
            unsigned r = __hip_atomic_fetch_add(&bar[512], 1u, __ATOMIC_RELAXED, __HIP_MEMORY_SCOPE_AGENT);
            if (r == bk*16u + 15u)
                __hip_atomic_store(&bar[544], bk+1u, __ATOMIC_RELAXED, __HIP_MEMORY_SCOPE_AGENT);
        }
        while (__hip_atomic_load(&bar[544], __ATOMIC_RELAXED, __HIP_MEMORY_SCOPE_AGENT) <= bk)
            __builtin_amdgcn_s_sleep(8);
    }
    __syncthreads();
}

// ---------------------------------------------------------------------------
// Prep (fp32 inputs): h fp32 master + bf16 copy; bf16-transposed weights.
// Separate kernel: its outputs land in memory via kernel-boundary flush.
// ---------------------------------------------------------------------------
__global__ __launch_bounds__(256) void k_prep(
    const float* __restrict__ node, const float* __restrict__ Wmsg,
    const float* __restrict__ Wi,   const float* __restrict__ Wh,
    const float* __restrict__ Ar,
    float* __restrict__ h32, bf16* __restrict__ hb,
    bf16* __restrict__ WmT, bf16* __restrict__ WiT, bf16* __restrict__ WhT,
    bf16* __restrict__ ArT)
{
    int tid = blockIdx.x*256 + threadIdx.x;
    int stride = gridDim.x*256;
    for (int i = tid; i < Nn*Dd; i += stride){
        float v = node[i]; h32[i] = v; hb[i] = (bf16)v;
    }
    for (int i = tid; i < Ee*Dd*Dd; i += stride){
        int e = i >> 14; int r = i & 16383; int h = r >> 7; int d = r & 127;
        WmT[i] = (bf16)Wmsg[e*Dd*Dd + d*Dd + h];
    }
    for (int i = tid; i < 384*Dd; i += stride){
        int j = i >> 7; int d = i & 127;
        WiT[i] = (bf16)Wi[d*384 + j];
        WhT[i] = (bf16)Wh[d*384 + j];
    }
    for (int i = tid; i < Dd*Dd; i += stride){
        int h = i >> 7; int d = i & 127;
        ArT[i] = (bf16)Ar[d*Dd + h];
    }
}

// ======================== mega-kernel phases ===============================

static __device__ __forceinline__ void phase_conv(
    int bid, const float* __restrict__ edge, bf16* __restrict__ edge_bf)
{
    const size_t total = (size_t)Nn*Nn*Ee;
    size_t base = ((size_t)bid*256 + threadIdx.x)*8;
    size_t stride = (size_t)NBLK*256*8;
    for (size_t i = base; i < total; i += stride){
        f32x4 v0 = *(const f32x4*)&edge[i];
        f32x4 v1 = *(const f32x4*)&edge[i+4];
        bf16x8 o;
        for (int j = 0; j < 4; j++){ o[j] = (bf16)v0[j]; o[j+4] = (bf16)v1[j]; }
        *(bf16x8*)&edge_bf[i] = o;   // cached; flushed by the one fenced barrier
    }
}

// Pt[h][s*8+e] = (hb @ W_e)[s][h]; active bid<256 -> (s-tile 64, h-tile 16)
static __device__ __forceinline__ void phase_perE(
    int bid, const bf16* __restrict__ hb, const bf16* __restrict__ WmT,
    bf16* __restrict__ Pt, char* smem)
{
    bf16 (*Blds)[16][136] = (bf16(*)[16][136])smem;   // 34816 B
    const int s0 = (bid & 31) * 64;
    const int h0 = (bid >> 5) * 16;
    const int tid = threadIdx.x;
    for (int i = 0; i < 8; i++){
        int idx = tid + i*256;
        int e = idx >> 8, row = (idx >> 4) & 15, c = idx & 15;
        *(bf16x8*)&Blds[e][row][c*8] =
            *(const bf16x8*)&WmT[e*Dd*Dd + (h0+row)*Dd + c*8];
    }
    __syncthreads();
    const int lane = tid & 63, wave = tid >> 6;
    const int quad = lane >> 4, l16 = lane & 15;
    const int srow = s0 + wave*16 + l16;
    f32x4 acc[Ee];
    for (int e = 0; e < Ee; e++) acc[e] = (f32x4){0.f,0.f,0.f,0.f};
    for (int kk = 0; kk < 4; kk++){
        int k0 = kk*32 + quad*8;
        bf16x8 a = ldg_frag(&hb[srow*Dd + k0]);        // uncached (gru writes it)
        for (int e = 0; e < Ee; e++){
            bf16x8 b = *(const bf16x8*)&Blds[e][l16][k0];
            acc[e] = mfma16(a, b, acc[e]);
        }
    }
    const int h = h0 + l16;
    for (int r = 0; r < 4; r++){
        int s = s0 + wave*16 + quad*4 + r;
        union { u32 u[4]; bf16x8 v; } w;
        for (int e = 0; e < Ee; e++) w.v[e] = (bf16)acc[e][r];
        u32* dst = (u32*)&Pt[(size_t)h*KT + s*Ee];
        stg_u32(dst+0, w.u[0]); stg_u32(dst+1, w.u[1]);
        stg_u32(dst+2, w.u[2]); stg_u32(dst+3, w.u[3]);
    }
}

// msgP[ks][t][h] partial GEMM; bid -> (t-tile of 128, ks of 32)
static __device__ __forceinline__ void phase_msgG(
    int bid, const bf16* __restrict__ edge_bf, const bf16* __restrict__ Pt,
    float* __restrict__ msgP, char* smem)
{
    bf16 (*Alds)[1032] = (bf16(*)[1032])smem;          // 16512 B
    bf16 (*Blds)[72]   = (bf16(*)[72])(smem + 16512);  // 18432 B
    const int t0 = (bid & 15) * 128;
    const int ks = bid >> 4;                            // 0..31
    const int kbase = ks * (KT/KSPLIT);                 // 512 k = 64 s
    const int tid = threadIdx.x;
    const int lane = tid & 63, wave = tid >> 6;
    const int quad = lane >> 4, l16 = lane & 15;
    const int wm = wave & 1, wn = wave >> 1;

    f32x4 acc[4][4];
    for (int mt = 0; mt < 4; mt++)
        for (int nt = 0; nt < 4; nt++) acc[mt][nt] = (f32x4){0.f,0.f,0.f,0.f};

    for (int ch = 0; ch < 8; ch++){
        const int kc = kbase + ch*64;
        const int sb = kc >> 3;
        for (int i = 0; i < 4; i++){
            int idx = tid + i*256;
            int sl = idx >> 7, off = idx & 127;
            *(bf16x8*)&Alds[sl][off*8] =                 // edge_bf cached (hot)
                *(const bf16x8*)&edge_bf[(size_t)(sb+sl)*(Nn*Ee) + (size_t)(t0+off)*Ee];
        }
        for (int i = 0; i < 4; i++){
            int idx = tid + i*256;
            int row = idx >> 3, c = idx & 7;
            const u32* src = (const u32*)&Pt[(size_t)row*KT + kc + c*8];
            u32* dst = (u32*)&Blds[row][c*8];
            dst[0]=ldg_u32(src+0); dst[1]=ldg_u32(src+1);
            dst[2]=ldg_u32(src+2); dst[3]=ldg_u32(src+3);
        }
        __syncthreads();
        for (int kk = 0; kk < 2; kk++){
            const int sl = kk*4 + quad;
            const int klb = kk*32 + quad*8;
            bf16x8 a[4], b[4];
            for (int mt = 0; mt < 4; mt++){
                int tp = wm*64 + mt*16 + l16;
                a[mt] = *(const bf16x8*)&Alds[sl][tp*8];
            }
            for (int nt = 0; nt < 4; nt++){
                int n = wn*64 + nt*16 + l16;
                b[nt] = *(const bf16x8*)&Blds[n][klb];
            }
            for (int mt = 0; mt < 4; mt++)
                for (int nt = 0; nt < 4; nt++)
                    acc[mt][nt] = mfma16(a[mt], b[nt], acc[mt][nt]);
        }
        __syncthreads();
    }
    float* dst = msgP + (size_t)ks*Nn*Dd;
    for (int mt = 0; mt < 4; mt++){
        for (int nt = 0; nt < 4; nt++){
            int h = wn*64 + nt*16 + l16;
            for (int r = 0; r < 4; r++){
                int t = t0 + wm*64 + mt*16 + quad*4 + r;
                stg_f32(&dst[(size_t)t*Dd + h], acc[mt][nt][r]);
            }
        }
    }
}

// GRU for 16 t-rows (active bid<128). msgP reduced once into LDS.
static __device__ __forceinline__ void phase_gru(
    int bid, const float* __restrict__ msgP, const bf16* __restrict__ WiT,
    const bf16* __restrict__ WhT, const float* __restrict__ bmsg,
    const float* __restrict__ bgru, float* __restrict__ h32,
    bf16* __restrict__ hb, char* smem)
{
    bf16 (*stage)[40] = (bf16(*)[40])smem;              // 30720 B
    float (*Gs)[388]  = (float(*)[388])(smem + 30720);  // 24832 B
    float (*Ghn)[132] = (float(*)[132])(smem + 55552);  //  8448 B -> 64000
    const int t0 = bid * 16;
    const int tid = threadIdx.x;
    for (int i = tid; i < 16*Dd; i += 256){
        int m = i >> 7, jd = i & 127;
        float s = bmsg[jd];
        const float* mp = &msgP[(size_t)(t0+m)*Dd + jd];
        #pragma unroll
        for (int p = 0; p < KSPLIT; p++) s += ldg_f32(&mp[(size_t)p*Nn*Dd]);
        Gs[m][jd] = s;
    }
    __syncthreads();
    const int lane = tid & 63, wave = tid >> 6;
    const int quad = lane >> 4, l16 = lane & 15;
    f32x4 accA[6], accB[6];
    for (int i = 0; i < 6; i++){ accA[i] = (f32x4){0.f,0.f,0.f,0.f}; accB[i] = (f32x4){0.f,0.f,0.f,0.f}; }
    for (int mat = 0; mat < 2; mat++){
        const bf16* WT = mat == 0 ? WiT : WhT;
        for (int kc = 0; kc < 4; kc++){
            for (int i = 0; i < 6; i++){
                int idx = tid + i*256; int row = idx >> 2, c = idx & 3;
                *(bf16x8*)&stage[row][c*8] = *(const bf16x8*)&WT[row*Dd + kc*32 + c*8];
            }
            __syncthreads();
            int k0 = kc*32 + quad*8;
            bf16x8 a;
            if (mat == 0){
                const float* gp = &Gs[l16][k0];
                for (int j = 0; j < 8; j++) a[j] = (bf16)gp[j];
            } else {
                a = ldg_frag(&hb[(t0 + l16)*Dd + k0]);
            }
            for (int tt = 0; tt < 6; tt++){
                int T = wave*6 + tt;
                bf16x8 b = *(const bf16x8*)&stage[T*16 + l16][quad*8];
                if (mat == 0 || T < 16) accA[tt] = mfma16(a, b, accA[tt]);
                else                    accB[tt] = mfma16(a, b, accB[tt]);
            }
            __syncthreads();
        }
    }
    for (int tt = 0; tt < 6; tt++){
        int T = wave*6 + tt;
        int j = T*16 + l16;
        for (int r = 0; r < 4; r++){
            int m = quad*4 + r;
            Gs[m][j] = accA[tt][r];
            if (T >= 16) Ghn[m][j - 256] = accB[tt][r];
        }
    }
    __syncthreads();
    for (int i = 0; i < 8; i++){
        int cell = tid + i*256;
        int m = cell >> 7, jd = cell & 127;
        int t = t0 + m;
        float xr = Gs[m][jd]       + bgru[jd];
        float xz = Gs[m][jd + 128] + bgru[jd + 128];
        float xn = Gs[m][jd + 256] + bgru[jd + 256];
        float r = 1.f / (1.f + expf(-xr));
        float z = 1.f / (1.f + expf(-xz));
        float n = tanhf(xn + r * Ghn[m][jd]);
        float ho = h32[t*Dd + jd];                      // block-private: cached
        float hnew = (1.f - z) * n + z * ho;
        h32[t*Dd + jd] = hnew;
        stg_u16((u16*)&hb[t*Dd + jd], bf_bits((bf16)hnew));
    }
}

// t1 = hb @ A_readout (active bid<32, s-tile of 64)
static __device__ __forceinline__ void phase_read1(
    int bid, const bf16* __restrict__ hb, const bf16* __restrict__ ArT,
    bf16* __restrict__ t1, char* smem)
{
    bf16 (*Blds)[136] = (bf16(*)[136])smem;
    const int s0 = bid * 64;
    const int tid = threadIdx.x;
    for (int i = 0; i < 8; i++){
        int idx = tid + i*256; int row = idx >> 4, c = idx & 15;
        *(bf16x8*)&Blds[row][c*8] = *(const bf16x8*)&ArT[row*Dd + c*8];
    }
    __syncthreads();
    const int lane = tid & 63, wave = tid >> 6;
    const int quad = lane >> 4, l16 = lane & 15;
    const int srow = s0 + wave*16 + l16;
    f32x4 acc[8];
    for (int nt = 0; nt < 8; nt++) acc[nt] = (f32x4){0.f,0.f,0.f,0.f};
    for (int kk = 0; kk < 4; kk++){
        int k0 = kk*32 + quad*8;
        bf16x8 a = ldg_frag(&hb[srow*Dd + k0]);
        for (int nt = 0; nt < 8; nt++){
            bf16x8 b = *(const bf16x8*)&Blds[nt*16 + l16][k0];
            acc[nt] = mfma16(a, b, acc[nt]);
        }
    }
    for (int nt = 0; nt < 8; nt++){
        int h = nt*16 + l16;
        for (int r = 0; r < 4; r++){
            int s = s0 + wave*16 + quad*4 + r;
            stg_u16((u16*)&t1[s*Dd + h], bf_bits((bf16)acc[nt][r]));
        }
    }
}

// logits[i][j] = sum_d t1[i][d]*hb[j][d]; active bid<256 -> (i,j tiles of 128)
static __device__ __forceinline__ void phase_read2(
    int bid, const bf16* __restrict__ t1, const bf16* __restrict__ hb,
    float* __restrict__ out)
{
    const int i0 = (bid & 15) * 128, j0 = (bid >> 4) * 128;
    const int tid = threadIdx.x;
    const int lane = tid & 63, wave = tid >> 6;
    const int quad = lane >> 4, l16 = lane & 15;
    const int wm = wave & 1, wn = wave >> 1;
    f32x4 acc[4][4];
    for (int mt = 0; mt < 4; mt++)
        for (int nt = 0; nt < 4; nt++) acc[mt][nt] = (f32x4){0.f,0.f,0.f,0.f};
    for (int kk = 0; kk < 4; kk++){
        int k0 = kk*32 + quad*8;
        bf16x8 a[4], b[4];
        for (int mt = 0; mt < 4; mt++)
            a[mt] = ldg_frag(&t1[(size_t)(i0 + wm*64 + mt*16 + l16)*Dd + k0]);
        for (int nt = 0; nt < 4; nt++)
            b[nt] = ldg_frag(&hb[(size_t)(j0 + wn*64 + nt*16 + l16)*Dd + k0]);
        for (int mt = 0; mt < 4; mt++)
            for (int nt = 0; nt < 4; nt++)
                acc[mt][nt] = mfma16(a[mt], b[nt], acc[mt][nt]);
    }
    for (int mt = 0; mt < 4; mt++){
        for (int nt = 0; nt < 4; nt++){
            int j = j0 + wn*64 + nt*16 + l16;
            for (int r = 0; r < 4; r++){
                int i = i0 + wm*64 + mt*16 + quad*4 + r;
                out[(size_t)i*Nn + j] = acc[mt][nt][r];   // last phase: cached, kernel-end flush
            }
        }
    }
}

// ---------------------------------------------------------------------------
// Persistent mega-kernel, fence-free barriers. 512 blocks, 2/CU.
// ---------------------------------------------------------------------------
__global__ __launch_bounds__(256, 2) void k_mega(
    const float* __restrict__ edge, bf16* __restrict__ edge_bf,
    const bf16* __restrict__ WmT, bf16* __restrict__ Pt,
    float* __restrict__ msgP,
    const bf16* __restrict__ WiT, const bf16* __restrict__ WhT,
    const float* __restrict__ bmsg, const float* __restrict__ bgru,
    float* __restrict__ h32, bf16* __restrict__ hb,
    const bf16* __restrict__ ArT, bf16* __restrict__ t1,
    float* __restrict__ out, unsigned* __restrict__ bar)
{
    __shared__ __align__(16) char smem[64000];
    const int bid = blockIdx.x;
    unsigned bk = 0;

    phase_conv(bid, edge, edge_bf);
    if (bid < 256) phase_perE(bid, hb, WmT, Pt, smem);
    gbar(bar, bk++, true);                    // the ONLY fenced barrier (edge_bf flush)
    for (int it = 0; it < NIT; it++){
        phase_msgG(bid, edge_bf, Pt, msgP, smem);
        gbar(bar, bk++, false);
        if (bid < 128) phase_gru(bid, msgP, WiT, WhT, bmsg, bgru, h32, hb, smem);
        gbar(bar, bk++, false);
        if (it < NIT-1){
            if (bid < 256) phase_perE(bid, hb, WmT, Pt, smem);
            gbar(bar, bk++, false);
        }
    }
    if (bid < 32) phase_read1(bid, hb, ArT, t1, smem);
    gbar(bar, bk++, false);
    if (bid < 256) phase_read2(bid, t1, hb, out);
}

// ---------------------------------------------------------------------------
extern "C" void kernel_launch(void* const* d_in, const int* in_sizes, int n_in,
                              void* d_out, int out_size, void* d_ws, size_t ws_size,
                              hipStream_t stream)
{
    const float* node = (const float*)d_in[0];
    const float* edge = (const float*)d_in[1];
    const float* Wmsg = (const float*)d_in[2];
    const float* bmsg = (const float*)d_in[3];
    const float* Wi   = (const float*)d_in[4];
    const float* Wh   = (const float*)d_in[5];
    const float* bgru = (const float*)d_in[6];
    const float* Ar   = (const float*)d_in[7];
    float* out = (float*)d_out;

    char* ws = (char*)d_ws;
    bf16*  edge_bf = (bf16*)ws;          ws += (size_t)Nn*Nn*Ee*2;      // 64 MiB
    float* msgP = (float*)ws;            ws += (size_t)KSPLIT*Nn*Dd*4;  // 32 MiB
    bf16*  Pt  = (bf16*)ws;              ws += (size_t)Dd*KT*2;         //  4 MiB
    float* h32 = (float*)ws;             ws += (size_t)Nn*Dd*4;
    bf16*  hb  = (bf16*)ws;              ws += (size_t)Nn*Dd*2;
    bf16*  WmT = (bf16*)ws;              ws += (size_t)Ee*Dd*Dd*2;
    bf16*  WiT = (bf16*)ws;              ws += (size_t)384*Dd*2;
    bf16*  WhT = (bf16*)ws;              ws += (size_t)384*Dd*2;
    bf16*  ArT = (bf16*)ws;              ws += (size_t)Dd*Dd*2;
    bf16*  t1  = (bf16*)ws;              ws += (size_t)Nn*Dd*2;
    unsigned* bar = (unsigned*)ws;       ws += 4096;

    hipMemsetAsync(bar, 0, 4096, stream);
    k_prep<<<dim3(256), 256, 0, stream>>>(node, Wmsg, Wi, Wh, Ar,
                                          h32, hb, WmT, WiT, WhT, ArT);
    k_mega<<<dim3(NBLK), 256, 0, stream>>>(edge, edge_bf, WmT, Pt, msgP,
                                           WiT, WhT, bmsg, bgru, h32, hb,
                                           ArT, t1, out, bar);
}